// Round 6
// baseline (296.587 us; speedup 1.0000x reference)
//
#include <hip/hip_runtime.h>

typedef _Float16 half8v __attribute__((ext_vector_type(8)));
typedef float f32x4 __attribute__((ext_vector_type(4)));

constexpr float INV4096 = 1.0f / 4096.0f;
constexpr float ALPHA = 10.0f;

__device__ __forceinline__ f32x4 mfma16(half8v a, half8v b, f32x4 c_) {
  return __builtin_amdgcn_mfma_f32_16x16x32_f16(a, b, c_, 0, 0, 0);
}
__device__ __forceinline__ void dma16(const void *g, void *l) {
  __builtin_amdgcn_global_load_lds(
      (const __attribute__((address_space(1))) void *)g,
      (__attribute__((address_space(3))) void *)l, 16, 0, 0);
}
template <int N> __device__ __forceinline__ void wait_vm() {
  asm volatile("s_waitcnt vmcnt(%0)" ::"n"(N) : "memory");
}

// ---- pre-split kernel: GW (64x1024 f32) and WN (64x64 f32) -> fp16 hi/lo ----
// ws image (bytes):
//   [0, 262144)        GW: 16 chunks x 16KB; chunk ck: hi[e][kk] at
//                      ck*16384 + e*128 + (((kk>>3)^(e&7))<<4) + (kk&7)*2, lo at +8192
//   [262144, 278528)   WN: same layout, single 16KB image (k = 0..63)
__global__ __launch_bounds__(256) void presplit(const float *__restrict__ GW,
                                                const float *__restrict__ WN,
                                                char *__restrict__ ws) {
  const int b = blockIdx.x;
  const int tid = threadIdx.x;
  if (b < 64) {
    int idx = b * 256 + tid;  // f32x4 index into GW
    int e = idx >> 8;
    int c4 = idx & 255;
    f32x4 v = *reinterpret_cast<const f32x4 *>(GW + (size_t)idx * 4);
#pragma unroll
    for (int j = 0; j < 4; ++j) {
      int k = c4 * 4 + j;
      float vv = v[j];
      _Float16 hh = (_Float16)vv;
      _Float16 ll = (_Float16)((vv - (float)hh) * 4096.0f);
      int ck = k >> 6, kk = k & 63;
      int off = ck * 16384 + e * 128 + ((((kk >> 3) ^ (e & 7))) << 4) + ((kk & 7) << 1);
      *reinterpret_cast<_Float16 *>(ws + off) = hh;
      *reinterpret_cast<_Float16 *>(ws + off + 8192) = ll;
    }
  } else {
    int idx = (b - 64) * 256 + tid;  // f32x4 index into WN [k][e0..e0+3]
    int k = idx >> 4;
    int e0 = (idx & 15) << 2;
    f32x4 v = *reinterpret_cast<const f32x4 *>(WN + (size_t)k * 64 + e0);
#pragma unroll
    for (int j = 0; j < 4; ++j) {
      int e = e0 + j;
      float vv = v[j];
      _Float16 hh = (_Float16)vv;
      _Float16 ll = (_Float16)((vv - (float)hh) * 4096.0f);
      int off = 262144 + e * 128 + ((((k >> 3) ^ (e & 7))) << 4) + ((k & 7) << 1);
      *reinterpret_cast<_Float16 *>(ws + off) = hh;
      *reinterpret_cast<_Float16 *>(ws + off + 8192) = ll;
    }
  }
}

// Macro-iteration structure: 4 macros x (K=256). Per macro each wave issues
// its A-loads as one contiguous 1KB-per-row burst (DRAM page locality) and
// DMAs 4 B sub-chunks (64KB) into a single LDS buffer.
// LDS map (64 KB): sub-chunk j of current macro at j*16384.
// Epilogue aliases: WN image -> [0,16384); clean tile -> 16384 + wv*4096.
__global__ __launch_bounds__(256, 2) void topk_gating(
    const float *__restrict__ X, const char *__restrict__ WS,
    const float *__restrict__ GB, const float *__restrict__ NZ,
    float *__restrict__ OUT) {
  __shared__ __align__(16) char lds[65536];
  const int tid = threadIdx.x;
  const int lane = tid & 63;
  const int wv = tid >> 6;
  const int q = lane >> 4;  // 0..3
  const int c = lane & 15;  // 0..15
  const int waveRow = blockIdx.x * 64 + wv * 16;

  f32x4 accH[4] = {};
  f32x4 accX[4] = {};
  f32x4 aR[4][4];  // A regs for the 4 sub-chunks of the current macro

  const float *xBase = X + (size_t)(waveRow + c) * 1024 + q * 8;
  const char *wsL = WS + wv * 1024 + lane * 16;  // per-lane global src base
  char *ldsL = lds + wv * 1024;                  // DMA dest (lane off implicit)

#define CONV(A, ah, al)                                           \
  {                                                               \
    _Pragma("unroll") for (int ks_ = 0; ks_ < 2; ++ks_)           \
        _Pragma("unroll") for (int j_ = 0; j_ < 8; ++j_) {        \
      float xv_ = A[ks_ * 2 + (j_ >> 2)][j_ & 3];                 \
      _Float16 hh_ = (_Float16)xv_;                               \
      ah[ks_][j_] = hh_;                                          \
      al[ks_][j_] = (_Float16)((xv_ - (float)hh_) * 4096.0f);     \
    }                                                             \
  }
#define MFMAB(BUF, ah, al)                                                 \
  {                                                                        \
    _Pragma("unroll") for (int ks_ = 0; ks_ < 2; ++ks_)                    \
        _Pragma("unroll") for (int t_ = 0; t_ < 4; ++t_) {                 \
      int e_ = t_ * 16 + c;                                                \
      int off_ = (BUF) + e_ * 128 + ((((ks_ * 4 + q) ^ (e_ & 7))) << 4);   \
      half8v bh_ = *reinterpret_cast<half8v *>(lds + off_);                \
      half8v bl_ = *reinterpret_cast<half8v *>(lds + off_ + 8192);         \
      accH[t_] = mfma16(ah[ks_], bh_, accH[t_]);                           \
      accX[t_] = mfma16(ah[ks_], bl_, accX[t_]);                           \
      accX[t_] = mfma16(al[ks_], bh_, accX[t_]);                           \
    }                                                                      \
  }
#define BAR() __builtin_amdgcn_s_barrier()

#pragma unroll
  for (int m = 0; m < 4; ++m) {
    // LDS is free here (prologue / previous macro's trailing barrier).
    // Issue B DMA for 4 sub-chunks (64 KB/block, L2-resident source).
#pragma unroll
    for (int j = 0; j < 4; ++j)
#pragma unroll
      for (int i = 0; i < 4; ++i)
        dma16(wsL + (m * 4 + j) * 16384 + i * 4096,
              ldsL + j * 16384 + i * 4096);
    // Issue A loads back-to-back: 16 loads covering a CONTIGUOUS 1KB window
    // per X-row (the DRAM-page-locality payload of this round).
#pragma unroll
    for (int s = 0; s < 4; ++s) {
      const float *xp = xBase + (m * 4 + s) * 64;
      aR[s][0] = *(const f32x4 *)(xp + 0);
      aR[s][1] = *(const f32x4 *)(xp + 4);
      aR[s][2] = *(const f32x4 *)(xp + 32);
      aR[s][3] = *(const f32x4 *)(xp + 36);
    }
    wait_vm<0>();
    BAR();  // B published
#pragma unroll
    for (int s = 0; s < 4; ++s) {
      half8v ah[2], al[2];
      CONV(aR[s], ah, al);
      MFMAB(s * 16384, ah, al);
    }
    BAR();  // all waves done reading this macro's B
  }

  // ---- epilogue ----
  // issue order (pinned): GB(4), WN-DMA(4) | fence | NZ(16)
  float bs0 = GB[c], bs1 = GB[16 + c], bs2 = GB[32 + c], bs3 = GB[48 + c];
#pragma unroll
  for (int i = 0; i < 4; ++i)
    dma16(wsL + 262144 + i * 4096, ldsL + i * 4096);  // WN -> [0,16K)
  asm volatile("" ::: "memory");
  float nz[4][4];
#pragma unroll
  for (int t = 0; t < 4; ++t)
#pragma unroll
    for (int r = 0; r < 4; ++r)
      nz[t][r] = NZ[(size_t)(waveRow + 4 * q + r) * 64 + t * 16 + c];

  float cl[4][4];  // [etile][reg]; element = (row 4q+r, expert 16t+c)
  const float bsv[4] = {bs0, bs1, bs2, bs3};
#pragma unroll
  for (int t = 0; t < 4; ++t)
#pragma unroll
    for (int r = 0; r < 4; ++r)
      cl[t][r] = accH[t][r] + accX[t][r] * INV4096 + bsv[t];

  // clean tile -> own-wave region at 16384 + wv*4096, swizzled
  char *cb = lds + 16384 + wv * 4096;
#pragma unroll
  for (int t = 0; t < 4; ++t)
#pragma unroll
    for (int r = 0; r < 4; ++r) {
      int row = 4 * q + r;
      int colf = t * 16 + c;
      int off = row * 256 + ((((colf >> 2) ^ row)) << 4) + ((colf & 3) << 2);
      *reinterpret_cast<float *>(cb + off) = cl[t][r];
    }
  wait_vm<16>();  // drains GB+WN; NZ(16) stays in flight
  BAR();

  // phase 2: raw = clean @ w_noise (split-fp16 MFMA, K=64); WN image at base 0
  f32x4 rH[4] = {};
  f32x4 rX[4] = {};
#pragma unroll
  for (int ks = 0; ks < 2; ++ks) {
    int slot0 = ks * 8 + q * 2;
    f32x4 va = *reinterpret_cast<f32x4 *>(cb + c * 256 + (((slot0 ^ c)) << 4));
    f32x4 vb = *reinterpret_cast<f32x4 *>(cb + c * 256 + ((((slot0 + 1) ^ c)) << 4));
    half8v ah, al;
#pragma unroll
    for (int j = 0; j < 4; ++j) {
      float v = va[j];
      _Float16 hh = (_Float16)v;
      ah[j] = hh;
      al[j] = (_Float16)((v - (float)hh) * 4096.0f);
      float v2 = vb[j];
      _Float16 h2 = (_Float16)v2;
      ah[4 + j] = h2;
      al[4 + j] = (_Float16)((v2 - (float)h2) * 4096.0f);
    }
#pragma unroll
    for (int t = 0; t < 4; ++t) {
      int e = t * 16 + c;
      int off = e * 128 + ((((ks * 4 + q) ^ (e & 7))) << 4);
      half8v bh = *reinterpret_cast<half8v *>(lds + off);
      half8v bl = *reinterpret_cast<half8v *>(lds + off + 8192);
      rH[t] = mfma16(ah, bh, rH[t]);
      rX[t] = mfma16(ah, bl, rX[t]);
      rX[t] = mfma16(al, bh, rX[t]);
    }
  }

  float lg[4][4];  // [r][t]
#pragma unroll
  for (int t = 0; t < 4; ++t)
#pragma unroll
    for (int r = 0; r < 4; ++r) {
      float raw = rH[t][r] + rX[t][r] * INV4096;
      float sp = fmaxf(raw, 0.0f) + __logf(1.0f + __expf(-fabsf(raw)));
      lg[r][t] = cl[t][r] + nz[t][r] * (sp + 1e-5f);
    }

#pragma unroll
  for (int r = 0; r < 4; ++r) {
    float v0 = lg[r][0], v1 = lg[r][1], v2 = lg[r][2], v3 = lg[r][3];
    // top-2: in-lane over 4, then xor-shuffle over the 16-lane group
    float a = fmaxf(v0, v1), b_ = fminf(v0, v1);
    float d1 = fmaxf(v2, v3), d2 = fminf(v2, v3);
    float m1 = fmaxf(a, d1);
    float m2 = fmaxf(fminf(a, d1), fmaxf(b_, d2));
#pragma unroll
    for (int s = 1; s <= 8; s <<= 1) {
      float om1 = __shfl_xor(m1, s, 64);
      float om2 = __shfl_xor(m2, s, 64);
      float hi = fmaxf(m1, om1);
      float lo = fminf(m1, om1);
      float sec = (m1 >= om1) ? m2 : om2;
      m2 = fmaxf(lo, sec);
      m1 = hi;
    }
    // softmax(logits)
    float se[4], ssum = 0.f;
#pragma unroll
    for (int t = 0; t < 4; ++t) {
      se[t] = __expf(lg[r][t] - m1);
      ssum += se[t];
    }
#pragma unroll
    for (int s = 1; s <= 8; s <<= 1) ssum += __shfl_xor(ssum, s, 64);
    float inv = 1.0f / ssum;
    float ov[4];
#pragma unroll
    for (int t = 0; t < 4; ++t) {
      float sm = se[t] * inv;
      float vlog = ALPHA * __logf(1.0f + sm);
      float vexp = ALPHA * (__expf(sm) - 1.0f);
      ov[t] = (lg[r][t] < m2) ? vlog : vexp;
    }
    // gates = softmax(out)
    float g = fmaxf(fmaxf(ov[0], ov[1]), fmaxf(ov[2], ov[3]));
#pragma unroll
    for (int s = 1; s <= 8; s <<= 1) g = fmaxf(g, __shfl_xor(g, s, 64));
    float gsum = 0.f;
#pragma unroll
    for (int t = 0; t < 4; ++t) {
      ov[t] = __expf(ov[t] - g);
      gsum += ov[t];
    }
#pragma unroll
    for (int s = 1; s <= 8; s <<= 1) gsum += __shfl_xor(gsum, s, 64);
    float ginv = 1.0f / gsum;
    size_t rowOff = (size_t)(waveRow + 4 * q + r) * 64;
#pragma unroll
    for (int t = 0; t < 4; ++t)
      OUT[rowOff + t * 16 + c] = ov[t] * ginv;
  }
}

extern "C" void kernel_launch(void *const *d_in, const int *in_sizes, int n_in,
                              void *d_out, int out_size, void *d_ws,
                              size_t ws_size, hipStream_t stream) {
  const float *x = (const float *)d_in[0];
  const float *gw = (const float *)d_in[1];
  const float *gb = (const float *)d_in[2];
  const float *wn = (const float *)d_in[3];
  const float *nz = (const float *)d_in[4];
  float *out = (float *)d_out;
  char *ws = (char *)d_ws;
  const int N = in_sizes[0] / 1024;

  hipLaunchKernelGGL(presplit, dim3(68), dim3(256), 0, stream, gw, wn, ws);
  hipLaunchKernelGGL(topk_gating, dim3(N / 64), dim3(256), 0, stream, x, ws,
                     gb, nz, out);
}

// Round 10
// 280.350 us; speedup vs baseline: 1.0579x; 1.0579x over previous
//
#include <hip/hip_runtime.h>

typedef _Float16 half8v __attribute__((ext_vector_type(8)));
typedef float f32x4 __attribute__((ext_vector_type(4)));

constexpr float INV4096 = 1.0f / 4096.0f;
constexpr float ALPHA = 10.0f;

__device__ __forceinline__ f32x4 mfma16(half8v a, half8v b, f32x4 c_) {
  return __builtin_amdgcn_mfma_f32_16x16x32_f16(a, b, c_, 0, 0, 0);
}
__device__ __forceinline__ void dma16(const void *g, void *l) {
  __builtin_amdgcn_global_load_lds(
      (const __attribute__((address_space(1))) void *)g,
      (__attribute__((address_space(3))) void *)l, 16, 0, 0);
}
template <int N> __device__ __forceinline__ void wait_vm() {
  asm volatile("s_waitcnt vmcnt(%0)" ::"n"(N) : "memory");
}
#define FENCE() asm volatile("" ::: "memory")
#define BAR()                            \
  do {                                   \
    __builtin_amdgcn_s_barrier();        \
    __builtin_amdgcn_sched_barrier(0);   \
  } while (0)

// ---- pre-split kernel: GW (64x1024 f32) and WN (64x64 f32) -> fp16 hi/lo ----
// ws image (bytes):
//   [0, 262144)        GW: 16 chunks x 16KB; chunk ck: hi[e][kk] at
//                      ck*16384 + e*128 + (((kk>>3)^(e&7))<<4) + (kk&7)*2, lo at +8192
//   [262144, 278528)   WN: same layout, single 16KB image (k = 0..63)
__global__ __launch_bounds__(256) void presplit(const float *__restrict__ GW,
                                                const float *__restrict__ WN,
                                                char *__restrict__ ws) {
  const int b = blockIdx.x;
  const int tid = threadIdx.x;
  if (b < 64) {
    int idx = b * 256 + tid;  // f32x4 index into GW
    int e = idx >> 8;
    int c4 = idx & 255;
    f32x4 v = *reinterpret_cast<const f32x4 *>(GW + (size_t)idx * 4);
#pragma unroll
    for (int j = 0; j < 4; ++j) {
      int k = c4 * 4 + j;
      float vv = v[j];
      _Float16 hh = (_Float16)vv;
      _Float16 ll = (_Float16)((vv - (float)hh) * 4096.0f);
      int ck = k >> 6, kk = k & 63;
      int off = ck * 16384 + e * 128 + ((((kk >> 3) ^ (e & 7))) << 4) + ((kk & 7) << 1);
      *reinterpret_cast<_Float16 *>(ws + off) = hh;
      *reinterpret_cast<_Float16 *>(ws + off + 8192) = ll;
    }
  } else {
    int idx = (b - 64) * 256 + tid;  // f32x4 index into WN [k][e0..e0+3]
    int k = idx >> 4;
    int e0 = (idx & 15) << 2;
    f32x4 v = *reinterpret_cast<const f32x4 *>(WN + (size_t)k * 64 + e0);
#pragma unroll
    for (int j = 0; j < 4; ++j) {
      int e = e0 + j;
      float vv = v[j];
      _Float16 hh = (_Float16)vv;
      _Float16 ll = (_Float16)((vv - (float)hh) * 4096.0f);
      int off = 262144 + e * 128 + ((((k >> 3) ^ (e & 7))) << 4) + ((k & 7) << 1);
      *reinterpret_cast<_Float16 *>(ws + off) = hh;
      *reinterpret_cast<_Float16 *>(ws + off + 8192) = ll;
    }
  }
}

// LDS map (80 KB):
//  [0, 32768)       A: 2 buffers x 16KB; chunk n in Abuf[n%2]. Wave-PRIVATE
//                   quadrant wv*4096: 16 rows x 256B, slot j of row r holds
//                   X cols ((j^(r&7))*4 ..+4). Written by the wave's OWN
//                   ds_write_b128 from line-coalesced register loads; read
//                   by its own ds_read_b128 fragments. No cross-wave A.
//  [32768, 81920)   B: 3 buffers x 16KB; chunk n in Bbuf[n%3] (hi 8K, lo 8K)
//                   via global_load_lds — EXACTLY R5's proven pipeline.
// Epilogue aliases: WN image -> Bbuf1 (49152); clean tile -> Bbuf2 + wv*4096.
// vmcnt ledger (fenced groups, per step issue [A-loads(4), B-dma(4)]):
// steady wait_vm<8> drains B(n+1), keeps {A(n+2),B(n+2)} in flight across
// the barrier. The compiler's own vmcnt before DSWA(n+1) drains A(n+1)
// while keeping B(n+1) (A issued before B). Tail: 8, 0.
__global__ __launch_bounds__(256, 2) void topk_gating(
    const float *__restrict__ X, const char *__restrict__ WS,
    const float *__restrict__ GB, const float *__restrict__ NZ,
    float *__restrict__ OUT) {
  __shared__ __align__(16) char lds[81920];
  const int tid = threadIdx.x;
  const int lane = tid & 63;
  const int wv = tid >> 6;
  const int q = lane >> 4;  // 0..3
  const int c = lane & 15;  // 0..15
  const int blockRow = blockIdx.x * 64;
  const int waveRow = blockRow + wv * 16;

  // A line-coalesced load geometry: lane = (r0 = lane>>3, s0 = lane&7).
  // Instr p covers 8 rows x one full 128B line:
  //  p0: rows r0,   slots s0    | p1: rows r0,   slots s0+8
  //  p2: rows r0+8, slots s0    | p3: rows r0+8, slots s0+8
  const int r0 = lane >> 3, s0 = lane & 7;
  const float *pC0 = X + (size_t)(waveRow + r0) * 1024 + s0 * 4;
  const float *pC1 = pC0 + 32;          // +128B (slots 8..15)
  const float *pC2 = pC0 + 8 * 1024;    // rows +8
  const float *pC3 = pC2 + 32;
  // ds_write target (swizzle slot^= row&7; rows r0 and r0+8 share r0&7=r0):
  const int aswz = wv * 4096 + r0 * 256 + ((s0 ^ r0) << 4);
  const char *wsL = WS + wv * 1024 + lane * 16;  // B per-lane global src
  // A fragment-read per-lane constants
  const int aRdB = wv * 4096 + (c << 8);
  const int xr = (c & 7) << 4;

  f32x4 accH[4] = {};
  f32x4 accX[4] = {};
  f32x4 rA[4];

#define ALOAD(KC)                                   \
  {                                                 \
    rA[0] = *(const f32x4 *)(pC0 + (KC) * 64);      \
    rA[1] = *(const f32x4 *)(pC1 + (KC) * 64);      \
    rA[2] = *(const f32x4 *)(pC2 + (KC) * 64);      \
    rA[3] = *(const f32x4 *)(pC3 + (KC) * 64);      \
  }
#define DSWA(KC)                                          \
  {                                                       \
    char *aw_ = lds + ((KC) % 2) * 16384 + aswz;          \
    *reinterpret_cast<f32x4 *>(aw_) = rA[0];              \
    *reinterpret_cast<f32x4 *>(aw_ + 128) = rA[1];        \
    *reinterpret_cast<f32x4 *>(aw_ + 2048) = rA[2];       \
    *reinterpret_cast<f32x4 *>(aw_ + 2176) = rA[3];       \
  }
#define BDMA(KC)                                                      \
  {                                                                   \
    char *bd_ = lds + 32768 + ((KC) % 3) * 16384 + wv * 1024;         \
    _Pragma("unroll") for (int i_ = 0; i_ < 4; ++i_)                  \
        dma16(wsL + (KC) * 16384 + i_ * 4096, bd_ + i_ * 4096);       \
  }
#define STEPC(KC)                                                            \
  {                                                                          \
    const int ab_ = ((KC) % 2) * 16384;                                      \
    const int bb_ = 32768 + ((KC) % 3) * 16384;                              \
    _Pragma("unroll") for (int ks_ = 0; ks_ < 2; ++ks_) {                    \
      int s0_ = ((ks_ * 8 + q * 2) << 4) ^ xr;                               \
      f32x4 va_ = *reinterpret_cast<f32x4 *>(lds + ab_ + aRdB + s0_);        \
      f32x4 vb_ = *reinterpret_cast<f32x4 *>(lds + ab_ + aRdB + (s0_ ^ 16)); \
      half8v ah_, al_;                                                       \
      _Pragma("unroll") for (int j_ = 0; j_ < 4; ++j_) {                     \
        float v1_ = va_[j_], v2_ = vb_[j_];                                  \
        _Float16 h1_ = (_Float16)v1_, h2_ = (_Float16)v2_;                   \
        ah_[j_] = h1_;                                                       \
        al_[j_] = (_Float16)((v1_ - (float)h1_) * 4096.0f);                  \
        ah_[4 + j_] = h2_;                                                   \
        al_[4 + j_] = (_Float16)((v2_ - (float)h2_) * 4096.0f);              \
      }                                                                      \
      _Pragma("unroll") for (int t_ = 0; t_ < 4; ++t_) {                     \
        int e_ = t_ * 16 + c;                                                \
        int off_ = bb_ + e_ * 128 + ((((ks_ * 4 + q) ^ (e_ & 7))) << 4);     \
        half8v bh_ = *reinterpret_cast<half8v *>(lds + off_);                \
        half8v bl_ = *reinterpret_cast<half8v *>(lds + off_ + 8192);         \
        accH[t_] = mfma16(ah_, bh_, accH[t_]);                               \
        accX[t_] = mfma16(ah_, bl_, accX[t_]);                               \
        accX[t_] = mfma16(al_, bh_, accX[t_]);                               \
      }                                                                      \
    }                                                                        \
  }
#define STEP(N)                          \
  {                                      \
    if ((N) + 1 <= 15) DSWA((N) + 1);    \
    FENCE();                             \
    if ((N) + 2 <= 15) ALOAD((N) + 2);   \
    FENCE();                             \
    if ((N) + 2 <= 15) BDMA((N) + 2);    \
    FENCE();                             \
    STEPC(N);                            \
  }

  // prologue: A0 loaded+written, A1 loaded; B0,B1 staged.
  // In-flight at wait: A1(4)+B0(4)+B1(4)=12 -> wait_vm<4> drains A1,B0;
  // keeps B1 in flight across the barrier.
  ALOAD(0); FENCE();
  DSWA(0);  FENCE();
  ALOAD(1); FENCE();
  BDMA(0);  FENCE();
  BDMA(1);  FENCE();
  wait_vm<4>(); BAR();

  STEP(0)  wait_vm<8>(); BAR();
  STEP(1)  wait_vm<8>(); BAR();
  STEP(2)  wait_vm<8>(); BAR();
  STEP(3)  wait_vm<8>(); BAR();
  STEP(4)  wait_vm<8>(); BAR();
  STEP(5)  wait_vm<8>(); BAR();
  STEP(6)  wait_vm<8>(); BAR();
  STEP(7)  wait_vm<8>(); BAR();
  STEP(8)  wait_vm<8>(); BAR();
  STEP(9)  wait_vm<8>(); BAR();
  STEP(10) wait_vm<8>(); BAR();
  STEP(11) wait_vm<8>(); BAR();
  STEP(12) wait_vm<8>(); BAR();
  STEP(13) wait_vm<8>(); BAR();  // drains B14; keeps {A15,B15}
  STEP(14) wait_vm<0>(); BAR();  // DSWA(15) drains A15; wait drains B15
  STEP(15)                       // compute only; epilogue uses Bbuf1/Bbuf2

  // ---- epilogue ----
  // issue order (pinned): GB(4), WN-DMA(4) | fence | NZ(16)
  float bs0 = GB[c], bs1 = GB[16 + c], bs2 = GB[32 + c], bs3 = GB[48 + c];
#pragma unroll
  for (int i = 0; i < 4; ++i)
    dma16(wsL + 262144 + i * 4096, lds + 49152 + wv * 1024 + i * 4096);
  FENCE();
  float nz[4][4];
#pragma unroll
  for (int t = 0; t < 4; ++t)
#pragma unroll
    for (int r = 0; r < 4; ++r)
      nz[t][r] = NZ[(size_t)(waveRow + 4 * q + r) * 64 + t * 16 + c];

  float cl[4][4];  // [etile][reg]; element = (row 4q+r, expert 16t+c)
  const float bsv[4] = {bs0, bs1, bs2, bs3};
#pragma unroll
  for (int t = 0; t < 4; ++t)
#pragma unroll
    for (int r = 0; r < 4; ++r)
      cl[t][r] = accH[t][r] + accX[t][r] * INV4096 + bsv[t];

  // clean tile -> own-wave quadrant of Bbuf2 (dead since barrier 14), swizzled
  char *cb = lds + 65536 + wv * 4096;
#pragma unroll
  for (int t = 0; t < 4; ++t)
#pragma unroll
    for (int r = 0; r < 4; ++r) {
      int row = 4 * q + r;
      int colf = t * 16 + c;
      int off = row * 256 + ((((colf >> 2) ^ row)) << 4) + ((colf & 3) << 2);
      *reinterpret_cast<float *>(cb + off) = cl[t][r];
    }
  wait_vm<16>();  // drains GB+WN; NZ(16) stays in flight
  BAR();

  // phase 2: raw = clean @ w_noise (split-fp16 MFMA, K=64); WN image at 49152
  f32x4 rH[4] = {};
  f32x4 rX[4] = {};
#pragma unroll
  for (int ks = 0; ks < 2; ++ks) {
    int slot0 = ks * 8 + q * 2;
    f32x4 va = *reinterpret_cast<f32x4 *>(cb + c * 256 + (((slot0 ^ c)) << 4));
    f32x4 vb = *reinterpret_cast<f32x4 *>(cb + c * 256 + ((((slot0 + 1) ^ c)) << 4));
    half8v ah, al;
#pragma unroll
    for (int j = 0; j < 4; ++j) {
      float v = va[j];
      _Float16 hh = (_Float16)v;
      ah[j] = hh;
      al[j] = (_Float16)((v - (float)hh) * 4096.0f);
      float v2 = vb[j];
      _Float16 h2 = (_Float16)v2;
      ah[4 + j] = h2;
      al[4 + j] = (_Float16)((v2 - (float)h2) * 4096.0f);
    }
#pragma unroll
    for (int t = 0; t < 4; ++t) {
      int e = t * 16 + c;
      int off = 49152 + e * 128 + ((((ks * 4 + q) ^ (e & 7))) << 4);
      half8v bh = *reinterpret_cast<half8v *>(lds + off);
      half8v bl = *reinterpret_cast<half8v *>(lds + off + 8192);
      rH[t] = mfma16(ah, bh, rH[t]);
      rX[t] = mfma16(ah, bl, rX[t]);
      rX[t] = mfma16(al, bh, rX[t]);
    }
  }

  float lg[4][4];  // [r][t]
#pragma unroll
  for (int t = 0; t < 4; ++t)
#pragma unroll
    for (int r = 0; r < 4; ++r) {
      float raw = rH[t][r] + rX[t][r] * INV4096;
      float sp = fmaxf(raw, 0.0f) + __logf(1.0f + __expf(-fabsf(raw)));
      lg[r][t] = cl[t][r] + nz[t][r] * (sp + 1e-5f);
    }

#pragma unroll
  for (int r = 0; r < 4; ++r) {
    float v0 = lg[r][0], v1 = lg[r][1], v2 = lg[r][2], v3 = lg[r][3];
    // top-2: in-lane over 4, then xor-shuffle over the 16-lane group
    float a = fmaxf(v0, v1), b_ = fminf(v0, v1);
    float d1 = fmaxf(v2, v3), d2 = fminf(v2, v3);
    float m1 = fmaxf(a, d1);
    float m2 = fmaxf(fminf(a, d1), fmaxf(b_, d2));
#pragma unroll
    for (int s = 1; s <= 8; s <<= 1) {
      float om1 = __shfl_xor(m1, s, 64);
      float om2 = __shfl_xor(m2, s, 64);
      float hi = fmaxf(m1, om1);
      float lo = fminf(m1, om1);
      float sec = (m1 >= om1) ? m2 : om2;
      m2 = fmaxf(lo, sec);
      m1 = hi;
    }
    // softmax(logits)
    float se[4], ssum = 0.f;
#pragma unroll
    for (int t = 0; t < 4; ++t) {
      se[t] = __expf(lg[r][t] - m1);
      ssum += se[t];
    }
#pragma unroll
    for (int s = 1; s <= 8; s <<= 1) ssum += __shfl_xor(ssum, s, 64);
    float inv = 1.0f / ssum;
    float ov[4];
#pragma unroll
    for (int t = 0; t < 4; ++t) {
      float sm = se[t] * inv;
      float vlog = ALPHA * __logf(1.0f + sm);
      float vexp = ALPHA * (__expf(sm) - 1.0f);
      ov[t] = (lg[r][t] < m2) ? vlog : vexp;
    }
    // gates = softmax(out)
    float g = fmaxf(fmaxf(ov[0], ov[1]), fmaxf(ov[2], ov[3]));
#pragma unroll
    for (int s = 1; s <= 8; s <<= 1) g = fmaxf(g, __shfl_xor(g, s, 64));
    float gsum = 0.f;
#pragma unroll
    for (int t = 0; t < 4; ++t) {
      ov[t] = __expf(ov[t] - g);
      gsum += ov[t];
    }
#pragma unroll
    for (int s = 1; s <= 8; s <<= 1) gsum += __shfl_xor(gsum, s, 64);
    float ginv = 1.0f / gsum;
    size_t rowOff = (size_t)(waveRow + 4 * q + r) * 64;
#pragma unroll
    for (int t = 0; t < 4; ++t)
      OUT[rowOff + t * 16 + c] = ov[t] * ginv;
  }
}

extern "C" void kernel_launch(void *const *d_in, const int *in_sizes, int n_in,
                              void *d_out, int out_size, void *d_ws,
                              size_t ws_size, hipStream_t stream) {
  const float *x = (const float *)d_in[0];
  const float *gw = (const float *)d_in[1];
  const float *gb = (const float *)d_in[2];
  const float *wn = (const float *)d_in[3];
  const float *nz = (const float *)d_in[4];
  float *out = (float *)d_out;
  char *ws = (char *)d_ws;
  const int N = in_sizes[0] / 1024;

  hipLaunchKernelGGL(presplit, dim3(68), dim3(256), 0, stream, gw, wn, ws);
  hipLaunchKernelGGL(topk_gating, dim3(N / 64), dim3(256), 0, stream, x, ws,
                     gb, nz, out);
}

// Round 11
// 270.487 us; speedup vs baseline: 1.0965x; 1.0365x over previous
//
#include <hip/hip_runtime.h>

typedef _Float16 half8v __attribute__((ext_vector_type(8)));
typedef float f32x4 __attribute__((ext_vector_type(4)));

constexpr float INV4096 = 1.0f / 4096.0f;
constexpr float ALPHA = 10.0f;

__device__ __forceinline__ f32x4 mfma16(half8v a, half8v b, f32x4 c_) {
  return __builtin_amdgcn_mfma_f32_16x16x32_f16(a, b, c_, 0, 0, 0);
}
__device__ __forceinline__ void dma16(const void *g, void *l) {
  __builtin_amdgcn_global_load_lds(
      (const __attribute__((address_space(1))) void *)g,
      (__attribute__((address_space(3))) void *)l, 16, 0, 0);
}
template <int N> __device__ __forceinline__ void wait_vm() {
  asm volatile("s_waitcnt vmcnt(%0)" ::"n"(N) : "memory");
}
#define FENCE() asm volatile("" ::: "memory")
#define BAR()                            \
  do {                                   \
    __builtin_amdgcn_s_barrier();        \
    __builtin_amdgcn_sched_barrier(0);   \
  } while (0)

// ---- pre-split kernel: GW (64x1024 f32) and WN (64x64 f32) -> fp16 hi/lo ----
// ws image (bytes):
//   [0, 262144)        GW: 16 chunks x 16KB; chunk ck: hi[e][kk] at
//                      ck*16384 + e*128 + (((kk>>3)^(e&7))<<4) + (kk&7)*2, lo at +8192
//   [262144, 278528)   WN: same layout, single 16KB image (k = 0..63)
__global__ __launch_bounds__(256) void presplit(const float *__restrict__ GW,
                                                const float *__restrict__ WN,
                                                char *__restrict__ ws) {
  const int b = blockIdx.x;
  const int tid = threadIdx.x;
  if (b < 64) {
    int idx = b * 256 + tid;  // f32x4 index into GW
    int e = idx >> 8;
    int c4 = idx & 255;
    f32x4 v = *reinterpret_cast<const f32x4 *>(GW + (size_t)idx * 4);
#pragma unroll
    for (int j = 0; j < 4; ++j) {
      int k = c4 * 4 + j;
      float vv = v[j];
      _Float16 hh = (_Float16)vv;
      _Float16 ll = (_Float16)((vv - (float)hh) * 4096.0f);
      int ck = k >> 6, kk = k & 63;
      int off = ck * 16384 + e * 128 + ((((kk >> 3) ^ (e & 7))) << 4) + ((kk & 7) << 1);
      *reinterpret_cast<_Float16 *>(ws + off) = hh;
      *reinterpret_cast<_Float16 *>(ws + off + 8192) = ll;
    }
  } else {
    int idx = (b - 64) * 256 + tid;  // f32x4 index into WN [k][e0..e0+3]
    int k = idx >> 4;
    int e0 = (idx & 15) << 2;
    f32x4 v = *reinterpret_cast<const f32x4 *>(WN + (size_t)k * 64 + e0);
#pragma unroll
    for (int j = 0; j < 4; ++j) {
      int e = e0 + j;
      float vv = v[j];
      _Float16 hh = (_Float16)vv;
      _Float16 ll = (_Float16)((vv - (float)hh) * 4096.0f);
      int off = 262144 + e * 128 + ((((k >> 3) ^ (e & 7))) << 4) + ((k & 7) << 1);
      *reinterpret_cast<_Float16 *>(ws + off) = hh;
      *reinterpret_cast<_Float16 *>(ws + off + 8192) = ll;
    }
  }
}

// 128-row blocks (512 threads, 8 waves x 16 rows): the per-block B stream
// (256 KB, unchanged) amortizes over 2x the rows -> B L2/VMEM traffic halves;
// waves/CU 12 -> 16.
// LDS map (48 KB): 3 B-buffers x 16 KB, chunk n in buf[n%3].
// Epilogue (after post-loop barrier): clean tile -> [0,32768) (wave w at
// w*4096); WN image -> buf2 [32768,49152).
// vmcnt ledger (fenced groups, per iter issue [A(n+1) 4ops, B(n+2) 2ops]):
// CONV(n)'s implicit wait covers A(n) (older), keeping B(n+1) in flight
// through the MFMA block; explicit wait_vm<6> publishes B(n+1) and keeps
// {A(n+1), B(n+2)} live across the barrier. Tail: 6 (n=13), 4 (n=14), 0.
__global__ __launch_bounds__(512, 4) void topk_gating(
    const float *__restrict__ X, const char *__restrict__ WS,
    const float *__restrict__ GB, const float *__restrict__ NZ,
    float *__restrict__ OUT) {
  __shared__ __align__(16) char lds[49152];
  const int tid = threadIdx.x;
  const int lane = tid & 63;
  const int wv = tid >> 6;  // 0..7
  const int q = lane >> 4;  // 0..3
  const int c = lane & 15;  // 0..15
  const int waveRow = blockIdx.x * 128 + wv * 16;

  f32x4 accH[4] = {};
  f32x4 accX[4] = {};
  f32x4 a0[4], a1[4];  // 2 A banks; chunk n in bank n%2 (depth-1 prefetch)

  const float *xBase = X + (size_t)(waveRow + c) * 1024 + q * 8;
  const char *wsL = WS + wv * 2048 + lane * 16;  // B per-lane global src

#define LDA4(dst, p)                        \
  {                                         \
    dst[0] = *(const f32x4 *)((p) + 0);     \
    dst[1] = *(const f32x4 *)((p) + 4);     \
    dst[2] = *(const f32x4 *)((p) + 32);    \
    dst[3] = *(const f32x4 *)((p) + 36);    \
  }
// 2 ops/wave: wave w covers [w*2048 + j*1024, +1024) of the 16KB chunk image
#define BDMA(CK)                                                      \
  {                                                                   \
    char *bd_ = lds + ((CK) % 3) * 16384 + wv * 2048;                 \
    dma16(wsL + (CK) * 16384, bd_);                                   \
    dma16(wsL + (CK) * 16384 + 1024, bd_ + 1024);                     \
  }
#define CONV(A, ah, al)                                           \
  {                                                               \
    _Pragma("unroll") for (int ks_ = 0; ks_ < 2; ++ks_)           \
        _Pragma("unroll") for (int j_ = 0; j_ < 8; ++j_) {        \
      float xv_ = A[ks_ * 2 + (j_ >> 2)][j_ & 3];                 \
      _Float16 hh_ = (_Float16)xv_;                               \
      ah[ks_][j_] = hh_;                                          \
      al[ks_][j_] = (_Float16)((xv_ - (float)hh_) * 4096.0f);     \
    }                                                             \
  }
#define MFMAB(BUF, ah, al)                                                 \
  {                                                                        \
    _Pragma("unroll") for (int ks_ = 0; ks_ < 2; ++ks_)                    \
        _Pragma("unroll") for (int t_ = 0; t_ < 4; ++t_) {                 \
      int e_ = t_ * 16 + c;                                                \
      int off_ = (BUF) + e_ * 128 + ((((ks_ * 4 + q) ^ (e_ & 7))) << 4);   \
      half8v bh_ = *reinterpret_cast<half8v *>(lds + off_);                \
      half8v bl_ = *reinterpret_cast<half8v *>(lds + off_ + 8192);         \
      accH[t_] = mfma16(ah[ks_], bh_, accH[t_]);                           \
      accX[t_] = mfma16(ah[ks_], bl_, accX[t_]);                           \
      accX[t_] = mfma16(al[ks_], bh_, accX[t_]);                           \
    }                                                                      \
  }
// Iter N: issue A(N+1) then B(N+2); CONV(N)'s implicit A-wait keeps the
// newer B(N+1) in flight; MFMA on buf[N%3].
#define STEP(N, AC, AN)                                          \
  {                                                              \
    half8v ah[2], al[2];                                         \
    if ((N) + 1 <= 15) LDA4(AN, xBase + ((N) + 1) * 64);         \
    FENCE();                                                     \
    if ((N) + 2 <= 15) BDMA((N) + 2);                            \
    FENCE();                                                     \
    CONV(AC, ah, al);                                            \
    MFMAB(((N) % 3) * 16384, ah, al);                            \
  }

  // prologue: order [B0, A0, B1] so A0 is OLDER than B1 (CONV(0)'s wait
  // then keeps B1 in flight). wait_vm<6> publishes B0, keeps {A0, B1}.
  BDMA(0); FENCE();
  LDA4(a0, xBase); FENCE();
  BDMA(1); FENCE();
  wait_vm<6>(); BAR();

  STEP(0, a0, a1)  wait_vm<6>(); BAR();
  STEP(1, a1, a0)  wait_vm<6>(); BAR();
  STEP(2, a0, a1)  wait_vm<6>(); BAR();
  STEP(3, a1, a0)  wait_vm<6>(); BAR();
  STEP(4, a0, a1)  wait_vm<6>(); BAR();
  STEP(5, a1, a0)  wait_vm<6>(); BAR();
  STEP(6, a0, a1)  wait_vm<6>(); BAR();
  STEP(7, a1, a0)  wait_vm<6>(); BAR();
  STEP(8, a0, a1)  wait_vm<6>(); BAR();
  STEP(9, a1, a0)  wait_vm<6>(); BAR();
  STEP(10, a0, a1) wait_vm<6>(); BAR();
  STEP(11, a1, a0) wait_vm<6>(); BAR();
  STEP(12, a0, a1) wait_vm<6>(); BAR();
  STEP(13, a1, a0) wait_vm<6>(); BAR();  // drains B14; keeps {A14? -> A14 consumed} {B15,A15 pattern per ledger}
  STEP(14, a0, a1) wait_vm<4>(); BAR();  // drains B15; keeps A15
  STEP(15, a1, a0)                        // compute only (buf0)
  BAR();  // all waves done with buf0 before epilogue aliases LDS

  // ---- epilogue ----
  // issue order (pinned): GB(4), WN-DMA(2) | fence | NZ(16)
  float bs0 = GB[c], bs1 = GB[16 + c], bs2 = GB[32 + c], bs3 = GB[48 + c];
  // WN image -> buf2 [32768,49152): wave w covers [w*2048, +2048)
  dma16(wsL + 262144, lds + 32768 + wv * 2048);
  dma16(wsL + 262144 + 1024, lds + 32768 + wv * 2048 + 1024);
  FENCE();
  float nz[4][4];
#pragma unroll
  for (int t = 0; t < 4; ++t)
#pragma unroll
    for (int r = 0; r < 4; ++r)
      nz[t][r] = NZ[(size_t)(waveRow + 4 * q + r) * 64 + t * 16 + c];

  float cl[4][4];  // [etile][reg]; element = (row 4q+r, expert 16t+c)
  const float bsv[4] = {bs0, bs1, bs2, bs3};
#pragma unroll
  for (int t = 0; t < 4; ++t)
#pragma unroll
    for (int r = 0; r < 4; ++r)
      cl[t][r] = accH[t][r] + accX[t][r] * INV4096 + bsv[t];

  // clean tile -> own-wave region of [0,32768) (buf0+buf1, dead), swizzled
  char *cb = lds + wv * 4096;
#pragma unroll
  for (int t = 0; t < 4; ++t)
#pragma unroll
    for (int r = 0; r < 4; ++r) {
      int row = 4 * q + r;
      int colf = t * 16 + c;
      int off = row * 256 + ((((colf >> 2) ^ row)) << 4) + ((colf & 3) << 2);
      *reinterpret_cast<float *>(cb + off) = cl[t][r];
    }
  wait_vm<16>();  // drains GB+WN; NZ(16) stays in flight
  BAR();

  // phase 2: raw = clean @ w_noise (split-fp16 MFMA, K=64); WN image at 32768
  f32x4 rH[4] = {};
  f32x4 rX[4] = {};
#pragma unroll
  for (int ks = 0; ks < 2; ++ks) {
    int slot0 = ks * 8 + q * 2;
    f32x4 va = *reinterpret_cast<f32x4 *>(cb + c * 256 + (((slot0 ^ c)) << 4));
    f32x4 vb = *reinterpret_cast<f32x4 *>(cb + c * 256 + ((((slot0 + 1) ^ c)) << 4));
    half8v ah, al;
#pragma unroll
    for (int j = 0; j < 4; ++j) {
      float v = va[j];
      _Float16 hh = (_Float16)v;
      ah[j] = hh;
      al[j] = (_Float16)((v - (float)hh) * 4096.0f);
      float v2 = vb[j];
      _Float16 h2 = (_Float16)v2;
      ah[4 + j] = h2;
      al[4 + j] = (_Float16)((v2 - (float)h2) * 4096.0f);
    }
#pragma unroll
    for (int t = 0; t < 4; ++t) {
      int e = t * 16 + c;
      int off = 32768 + e * 128 + ((((ks * 4 + q) ^ (e & 7))) << 4);
      half8v bh = *reinterpret_cast<half8v *>(lds + off);
      half8v bl = *reinterpret_cast<half8v *>(lds + off + 8192);
      rH[t] = mfma16(ah, bh, rH[t]);
      rX[t] = mfma16(ah, bl, rX[t]);
      rX[t] = mfma16(al, bh, rX[t]);
    }
  }

  float lg[4][4];  // [r][t]
#pragma unroll
  for (int t = 0; t < 4; ++t)
#pragma unroll
    for (int r = 0; r < 4; ++r) {
      float raw = rH[t][r] + rX[t][r] * INV4096;
      float sp = fmaxf(raw, 0.0f) + __logf(1.0f + __expf(-fabsf(raw)));
      lg[r][t] = cl[t][r] + nz[t][r] * (sp + 1e-5f);
    }

#pragma unroll
  for (int r = 0; r < 4; ++r) {
    float v0 = lg[r][0], v1 = lg[r][1], v2 = lg[r][2], v3 = lg[r][3];
    // top-2: in-lane over 4, then xor-shuffle over the 16-lane group
    float a = fmaxf(v0, v1), b_ = fminf(v0, v1);
    float d1 = fmaxf(v2, v3), d2 = fminf(v2, v3);
    float m1 = fmaxf(a, d1);
    float m2 = fmaxf(fminf(a, d1), fmaxf(b_, d2));
#pragma unroll
    for (int s = 1; s <= 8; s <<= 1) {
      float om1 = __shfl_xor(m1, s, 64);
      float om2 = __shfl_xor(m2, s, 64);
      float hi = fmaxf(m1, om1);
      float lo = fminf(m1, om1);
      float sec = (m1 >= om1) ? m2 : om2;
      m2 = fmaxf(lo, sec);
      m1 = hi;
    }
    // softmax(logits)
    float se[4], ssum = 0.f;
#pragma unroll
    for (int t = 0; t < 4; ++t) {
      se[t] = __expf(lg[r][t] - m1);
      ssum += se[t];
    }
#pragma unroll
    for (int s = 1; s <= 8; s <<= 1) ssum += __shfl_xor(ssum, s, 64);
    float inv = 1.0f / ssum;
    float ov[4];
#pragma unroll
    for (int t = 0; t < 4; ++t) {
      float sm = se[t] * inv;
      float vlog = ALPHA * __logf(1.0f + sm);
      float vexp = ALPHA * (__expf(sm) - 1.0f);
      ov[t] = (lg[r][t] < m2) ? vlog : vexp;
    }
    // gates = softmax(out)
    float g = fmaxf(fmaxf(ov[0], ov[1]), fmaxf(ov[2], ov[3]));
#pragma unroll
    for (int s = 1; s <= 8; s <<= 1) g = fmaxf(g, __shfl_xor(g, s, 64));
    float gsum = 0.f;
#pragma unroll
    for (int t = 0; t < 4; ++t) {
      ov[t] = __expf(ov[t] - g);
      gsum += ov[t];
    }
#pragma unroll
    for (int s = 1; s <= 8; s <<= 1) gsum += __shfl_xor(gsum, s, 64);
    float ginv = 1.0f / gsum;
    size_t rowOff = (size_t)(waveRow + 4 * q + r) * 64;
#pragma unroll
    for (int t = 0; t < 4; ++t)
      OUT[rowOff + t * 16 + c] = ov[t] * ginv;
  }
}

extern "C" void kernel_launch(void *const *d_in, const int *in_sizes, int n_in,
                              void *d_out, int out_size, void *d_ws,
                              size_t ws_size, hipStream_t stream) {
  const float *x = (const float *)d_in[0];
  const float *gw = (const float *)d_in[1];
  const float *gb = (const float *)d_in[2];
  const float *wn = (const float *)d_in[3];
  const float *nz = (const float *)d_in[4];
  float *out = (float *)d_out;
  char *ws = (char *)d_ws;
  const int N = in_sizes[0] / 1024;

  hipLaunchKernelGGL(presplit, dim3(68), dim3(256), 0, stream, gw, wn, ws);
  hipLaunchKernelGGL(topk_gating, dim3(N / 128), dim3(512), 0, stream, x, ws,
                     gb, nz, out);
}

// Round 12
// 260.054 us; speedup vs baseline: 1.1405x; 1.0401x over previous
//
#include <hip/hip_runtime.h>

typedef _Float16 half8v __attribute__((ext_vector_type(8)));
typedef float f32x4 __attribute__((ext_vector_type(4)));

constexpr float INV4096 = 1.0f / 4096.0f;
constexpr float ALPHA = 10.0f;

__device__ __forceinline__ f32x4 mfma16(half8v a, half8v b, f32x4 c_) {
  return __builtin_amdgcn_mfma_f32_16x16x32_f16(a, b, c_, 0, 0, 0);
}
__device__ __forceinline__ void dma16(const void *g, void *l) {
  __builtin_amdgcn_global_load_lds(
      (const __attribute__((address_space(1))) void *)g,
      (__attribute__((address_space(3))) void *)l, 16, 0, 0);
}
template <int N> __device__ __forceinline__ void wait_vm() {
  asm volatile("s_waitcnt vmcnt(%0)" ::"n"(N) : "memory");
}
#define FENCE() asm volatile("" ::: "memory")
#define BAR()                            \
  do {                                   \
    __builtin_amdgcn_s_barrier();        \
    __builtin_amdgcn_sched_barrier(0);   \
  } while (0)

// ---- pre-split kernel: GW (64x1024 f32) and WN (64x64 f32) -> fp16 hi/lo ----
// ws image (bytes):
//   [0, 262144)        GW: 16 chunks x 16KB; chunk ck: hi[e][kk] at
//                      ck*16384 + e*128 + (((kk>>3)^(e&7))<<4) + (kk&7)*2, lo at +8192
//   [262144, 278528)   WN: same layout, single 16KB image (k = 0..63)
__global__ __launch_bounds__(256) void presplit(const float *__restrict__ GW,
                                                const float *__restrict__ WN,
                                                char *__restrict__ ws) {
  const int b = blockIdx.x;
  const int tid = threadIdx.x;
  if (b < 64) {
    int idx = b * 256 + tid;  // f32x4 index into GW
    int e = idx >> 8;
    int c4 = idx & 255;
    f32x4 v = *reinterpret_cast<const f32x4 *>(GW + (size_t)idx * 4);
#pragma unroll
    for (int j = 0; j < 4; ++j) {
      int k = c4 * 4 + j;
      float vv = v[j];
      _Float16 hh = (_Float16)vv;
      _Float16 ll = (_Float16)((vv - (float)hh) * 4096.0f);
      int ck = k >> 6, kk = k & 63;
      int off = ck * 16384 + e * 128 + ((((kk >> 3) ^ (e & 7))) << 4) + ((kk & 7) << 1);
      *reinterpret_cast<_Float16 *>(ws + off) = hh;
      *reinterpret_cast<_Float16 *>(ws + off + 8192) = ll;
    }
  } else {
    int idx = (b - 64) * 256 + tid;  // f32x4 index into WN [k][e0..e0+3]
    int k = idx >> 4;
    int e0 = (idx & 15) << 2;
    f32x4 v = *reinterpret_cast<const f32x4 *>(WN + (size_t)k * 64 + e0);
#pragma unroll
    for (int j = 0; j < 4; ++j) {
      int e = e0 + j;
      float vv = v[j];
      _Float16 hh = (_Float16)vv;
      _Float16 ll = (_Float16)((vv - (float)hh) * 4096.0f);
      int off = 262144 + e * 128 + ((((k >> 3) ^ (e & 7))) << 4) + ((k & 7) << 1);
      *reinterpret_cast<_Float16 *>(ws + off) = hh;
      *reinterpret_cast<_Float16 *>(ws + off + 8192) = ll;
    }
  }
}

// R11 structure + paired A-loads (the clean 512B-burst test):
// 128-row blocks (512 threads, 8 waves x 16 rows). B: 3 x 16KB LDS buffers,
// chunk n in buf[n%3], staged 2 ops/wave via global_load_lds. A: 4 register
// banks, A(k) in bank k%4; EVEN steps load A(n+2) and A(n+3) back-to-back
// -> 8 dwordx4 covering a CONTIGUOUS 512B window per X-row.
// vmcnt ledger (B issued before A each step; uniform fenced groups):
//   prologue [B0,A0,A1,B1]=12, wait<6> drains B0,A0, keeps {A1,B1}.
//   even n: issue B(n+2),A(n+2),A(n+3); CONV(n) implicitly drains A(n);
//           end wait<10> drains {A(n+1),B(n+1)}, keeps {B(n+2),A(n+2),A(n+3)}.
//   odd n:  issue B(n+2); end wait<10> drains B(n+1),
//           keeps {A(n+1),A(n+2),B(n+2)}.
//   tail: n=14 issues nothing, wait<0>; n=15 compute-only.
// A slack in flight across barriers ~1.5-2.5 iters; B slack ~1 iter (L2).
// Epilogue (after post-loop BAR, identical to R11): clean -> [0,32768)
// (wave w at w*4096); WN image -> buf2 [32768,49152).
__global__ __launch_bounds__(512, 4) void topk_gating(
    const float *__restrict__ X, const char *__restrict__ WS,
    const float *__restrict__ GB, const float *__restrict__ NZ,
    float *__restrict__ OUT) {
  __shared__ __align__(16) char lds[49152];
  const int tid = threadIdx.x;
  const int lane = tid & 63;
  const int wv = tid >> 6;  // 0..7
  const int q = lane >> 4;  // 0..3
  const int c = lane & 15;  // 0..15
  const int waveRow = blockIdx.x * 128 + wv * 16;

  f32x4 accH[4] = {};
  f32x4 accX[4] = {};
  f32x4 a0[4], a1[4], a2[4], a3[4];  // A(k) lives in bank k%4

  const float *xBase = X + (size_t)(waveRow + c) * 1024 + q * 8;
  const char *wsL = WS + wv * 2048 + lane * 16;  // B per-lane global src

#define LDA4(dst, p)                        \
  {                                         \
    dst[0] = *(const f32x4 *)((p) + 0);     \
    dst[1] = *(const f32x4 *)((p) + 4);     \
    dst[2] = *(const f32x4 *)((p) + 32);    \
    dst[3] = *(const f32x4 *)((p) + 36);    \
  }
// 2 ops/wave: wave w covers [w*2048 + j*1024, +1024) of the 16KB chunk image
#define BDMA(CK)                                                      \
  {                                                                   \
    char *bd_ = lds + ((CK) % 3) * 16384 + wv * 2048;                 \
    dma16(wsL + (CK) * 16384, bd_);                                   \
    dma16(wsL + (CK) * 16384 + 1024, bd_ + 1024);                     \
  }
#define CONV(A, ah, al)                                           \
  {                                                               \
    _Pragma("unroll") for (int ks_ = 0; ks_ < 2; ++ks_)           \
        _Pragma("unroll") for (int j_ = 0; j_ < 8; ++j_) {        \
      float xv_ = A[ks_ * 2 + (j_ >> 2)][j_ & 3];                 \
      _Float16 hh_ = (_Float16)xv_;                               \
      ah[ks_][j_] = hh_;                                          \
      al[ks_][j_] = (_Float16)((xv_ - (float)hh_) * 4096.0f);     \
    }                                                             \
  }
#define MFMAB(BUF, ah, al)                                                 \
  {                                                                        \
    _Pragma("unroll") for (int ks_ = 0; ks_ < 2; ++ks_)                    \
        _Pragma("unroll") for (int t_ = 0; t_ < 4; ++t_) {                 \
      int e_ = t_ * 16 + c;                                                \
      int off_ = (BUF) + e_ * 128 + ((((ks_ * 4 + q) ^ (e_ & 7))) << 4);   \
      half8v bh_ = *reinterpret_cast<half8v *>(lds + off_);                \
      half8v bl_ = *reinterpret_cast<half8v *>(lds + off_ + 8192);         \
      accH[t_] = mfma16(ah[ks_], bh_, accH[t_]);                           \
      accX[t_] = mfma16(ah[ks_], bl_, accX[t_]);                           \
      accX[t_] = mfma16(al[ks_], bh_, accX[t_]);                           \
    }                                                                      \
  }
// Even step: issue B(N+2), then A(N+2)+A(N+3) back-to-back (512B/row burst).
#define STEPE(N, AC, AN2, AN3)                                   \
  {                                                              \
    half8v ah[2], al[2];                                         \
    if ((N) + 2 <= 15) {                                         \
      BDMA((N) + 2);                                             \
      FENCE();                                                   \
      LDA4(AN2, xBase + ((N) + 2) * 64);                         \
      LDA4(AN3, xBase + ((N) + 3) * 64);                         \
      FENCE();                                                   \
    }                                                            \
    CONV(AC, ah, al);                                            \
    MFMAB(((N) % 3) * 16384, ah, al);                            \
  }
// Odd step: issue B(N+2) only.
#define STEPO(N, AC)                                             \
  {                                                              \
    half8v ah[2], al[2];                                         \
    if ((N) + 2 <= 15) { BDMA((N) + 2); FENCE(); }               \
    CONV(AC, ah, al);                                            \
    MFMAB(((N) % 3) * 16384, ah, al);                            \
  }

  // prologue order [B0, A0, A1, B1] (12 ops); wait<6> drains B0,A0.
  BDMA(0); FENCE();
  LDA4(a0, xBase); FENCE();
  LDA4(a1, xBase + 64); FENCE();
  BDMA(1); FENCE();
  wait_vm<6>(); BAR();

  STEPE(0, a0, a2, a3)   wait_vm<10>(); BAR();
  STEPO(1, a1)           wait_vm<10>(); BAR();
  STEPE(2, a2, a0, a1)   wait_vm<10>(); BAR();
  STEPO(3, a3)           wait_vm<10>(); BAR();
  STEPE(4, a0, a2, a3)   wait_vm<10>(); BAR();
  STEPO(5, a1)           wait_vm<10>(); BAR();
  STEPE(6, a2, a0, a1)   wait_vm<10>(); BAR();
  STEPO(7, a3)           wait_vm<10>(); BAR();
  STEPE(8, a0, a2, a3)   wait_vm<10>(); BAR();
  STEPO(9, a1)           wait_vm<10>(); BAR();
  STEPE(10, a2, a0, a1)  wait_vm<10>(); BAR();
  STEPO(11, a3)          wait_vm<10>(); BAR();
  STEPE(12, a0, a2, a3)  wait_vm<10>(); BAR();  // loads A14->a2, A15->a3
  STEPO(13, a1)          wait_vm<10>(); BAR();  // B15; keeps {A14,A15,B15}
  STEPE(14, a2, a0, a1)  wait_vm<0>();  BAR();  // issues nothing; full drain
  STEPO(15, a3)                                  // compute only (buf0)
  BAR();  // all waves done with buf0 before epilogue aliases LDS

  // ---- epilogue (identical to R11) ----
  float bs0 = GB[c], bs1 = GB[16 + c], bs2 = GB[32 + c], bs3 = GB[48 + c];
  // WN image -> buf2 [32768,49152): wave w covers [w*2048, +2048)
  dma16(wsL + 262144, lds + 32768 + wv * 2048);
  dma16(wsL + 262144 + 1024, lds + 32768 + wv * 2048 + 1024);
  FENCE();
  float nz[4][4];
#pragma unroll
  for (int t = 0; t < 4; ++t)
#pragma unroll
    for (int r = 0; r < 4; ++r)
      nz[t][r] = NZ[(size_t)(waveRow + 4 * q + r) * 64 + t * 16 + c];

  float cl[4][4];  // [etile][reg]; element = (row 4q+r, expert 16t+c)
  const float bsv[4] = {bs0, bs1, bs2, bs3};
#pragma unroll
  for (int t = 0; t < 4; ++t)
#pragma unroll
    for (int r = 0; r < 4; ++r)
      cl[t][r] = accH[t][r] + accX[t][r] * INV4096 + bsv[t];

  // clean tile -> own-wave region of [0,32768) (buf0+buf1, dead), swizzled
  char *cb = lds + wv * 4096;
#pragma unroll
  for (int t = 0; t < 4; ++t)
#pragma unroll
    for (int r = 0; r < 4; ++r) {
      int row = 4 * q + r;
      int colf = t * 16 + c;
      int off = row * 256 + ((((colf >> 2) ^ row)) << 4) + ((colf & 3) << 2);
      *reinterpret_cast<float *>(cb + off) = cl[t][r];
    }
  wait_vm<16>();  // drains GB+WN; NZ(16) stays in flight
  BAR();

  // phase 2: raw = clean @ w_noise (split-fp16 MFMA, K=64); WN image at 32768
  f32x4 rH[4] = {};
  f32x4 rX[4] = {};
#pragma unroll
  for (int ks = 0; ks < 2; ++ks) {
    int slot0 = ks * 8 + q * 2;
    f32x4 va = *reinterpret_cast<f32x4 *>(cb + c * 256 + (((slot0 ^ c)) << 4));
    f32x4 vb = *reinterpret_cast<f32x4 *>(cb + c * 256 + ((((slot0 + 1) ^ c)) << 4));
    half8v ah, al;
#pragma unroll
    for (int j = 0; j < 4; ++j) {
      float v = va[j];
      _Float16 hh = (_Float16)v;
      ah[j] = hh;
      al[j] = (_Float16)((v - (float)hh) * 4096.0f);
      float v2 = vb[j];
      _Float16 h2 = (_Float16)v2;
      ah[4 + j] = h2;
      al[4 + j] = (_Float16)((v2 - (float)h2) * 4096.0f);
    }
#pragma unroll
    for (int t = 0; t < 4; ++t) {
      int e = t * 16 + c;
      int off = 32768 + e * 128 + ((((ks * 4 + q) ^ (e & 7))) << 4);
      half8v bh = *reinterpret_cast<half8v *>(lds + off);
      half8v bl = *reinterpret_cast<half8v *>(lds + off + 8192);
      rH[t] = mfma16(ah, bh, rH[t]);
      rX[t] = mfma16(ah, bl, rX[t]);
      rX[t] = mfma16(al, bh, rX[t]);
    }
  }

  float lg[4][4];  // [r][t]
#pragma unroll
  for (int t = 0; t < 4; ++t)
#pragma unroll
    for (int r = 0; r < 4; ++r) {
      float raw = rH[t][r] + rX[t][r] * INV4096;
      float sp = fmaxf(raw, 0.0f) + __logf(1.0f + __expf(-fabsf(raw)));
      lg[r][t] = cl[t][r] + nz[t][r] * (sp + 1e-5f);
    }

#pragma unroll
  for (int r = 0; r < 4; ++r) {
    float v0 = lg[r][0], v1 = lg[r][1], v2 = lg[r][2], v3 = lg[r][3];
    // top-2: in-lane over 4, then xor-shuffle over the 16-lane group
    float a = fmaxf(v0, v1), b_ = fminf(v0, v1);
    float d1 = fmaxf(v2, v3), d2 = fminf(v2, v3);
    float m1 = fmaxf(a, d1);
    float m2 = fmaxf(fminf(a, d1), fmaxf(b_, d2));
#pragma unroll
    for (int s = 1; s <= 8; s <<= 1) {
      float om1 = __shfl_xor(m1, s, 64);
      float om2 = __shfl_xor(m2, s, 64);
      float hi = fmaxf(m1, om1);
      float lo = fminf(m1, om1);
      float sec = (m1 >= om1) ? m2 : om2;
      m2 = fmaxf(lo, sec);
      m1 = hi;
    }
    // softmax(logits)
    float se[4], ssum = 0.f;
#pragma unroll
    for (int t = 0; t < 4; ++t) {
      se[t] = __expf(lg[r][t] - m1);
      ssum += se[t];
    }
#pragma unroll
    for (int s = 1; s <= 8; s <<= 1) ssum += __shfl_xor(ssum, s, 64);
    float inv = 1.0f / ssum;
    float ov[4];
#pragma unroll
    for (int t = 0; t < 4; ++t) {
      float sm = se[t] * inv;
      float vlog = ALPHA * __logf(1.0f + sm);
      float vexp = ALPHA * (__expf(sm) - 1.0f);
      ov[t] = (lg[r][t] < m2) ? vlog : vexp;
    }
    // gates = softmax(out)
    float g = fmaxf(fmaxf(ov[0], ov[1]), fmaxf(ov[2], ov[3]));
#pragma unroll
    for (int s = 1; s <= 8; s <<= 1) g = fmaxf(g, __shfl_xor(g, s, 64));
    float gsum = 0.f;
#pragma unroll
    for (int t = 0; t < 4; ++t) {
      ov[t] = __expf(ov[t] - g);
      gsum += ov[t];
    }
#pragma unroll
    for (int s = 1; s <= 8; s <<= 1) gsum += __shfl_xor(gsum, s, 64);
    float ginv = 1.0f / gsum;
    size_t rowOff = (size_t)(waveRow + 4 * q + r) * 64;
#pragma unroll
    for (int t = 0; t < 4; ++t)
      OUT[rowOff + t * 16 + c] = ov[t] * ginv;
  }
}

extern "C" void kernel_launch(void *const *d_in, const int *in_sizes, int n_in,
                              void *d_out, int out_size, void *d_ws,
                              size_t ws_size, hipStream_t stream) {
  const float *x = (const float *)d_in[0];
  const float *gw = (const float *)d_in[1];
  const float *gb = (const float *)d_in[2];
  const float *wn = (const float *)d_in[3];
  const float *nz = (const float *)d_in[4];
  float *out = (float *)d_out;
  char *ws = (char *)d_ws;
  const int N = in_sizes[0] / 1024;

  hipLaunchKernelGGL(presplit, dim3(68), dim3(256), 0, stream, gw, wn, ws);
  hipLaunchKernelGGL(topk_gating, dim3(N / 128), dim3(512), 0, stream, x, ws,
                     gb, nz, out);
}

// Round 13
// 259.126 us; speedup vs baseline: 1.1446x; 1.0036x over previous
//
#include <hip/hip_runtime.h>

typedef _Float16 half8v __attribute__((ext_vector_type(8)));
typedef float f32x4 __attribute__((ext_vector_type(4)));

constexpr float INV4096 = 1.0f / 4096.0f;
constexpr float ALPHA = 10.0f;

__device__ __forceinline__ f32x4 mfma16(half8v a, half8v b, f32x4 c_) {
  return __builtin_amdgcn_mfma_f32_16x16x32_f16(a, b, c_, 0, 0, 0);
}
__device__ __forceinline__ void dma16(const void *g, void *l) {
  __builtin_amdgcn_global_load_lds(
      (const __attribute__((address_space(1))) void *)g,
      (__attribute__((address_space(3))) void *)l, 16, 0, 0);
}
template <int N> __device__ __forceinline__ void wait_vm() {
  asm volatile("s_waitcnt vmcnt(%0)" ::"n"(N) : "memory");
}
#define FENCE() asm volatile("" ::: "memory")
#define BAR()                            \
  do {                                   \
    __builtin_amdgcn_s_barrier();        \
    __builtin_amdgcn_sched_barrier(0);   \
  } while (0)

// ---- pre-split kernel: GW (64x1024 f32) and WN (64x64 f32) -> fp16 hi/lo ----
// ws image (bytes):
//   [0, 262144)        GW: 16 chunks x 16KB; chunk ck: hi[e][kk] at
//                      ck*16384 + e*128 + (((kk>>3)^(e&7))<<4) + (kk&7)*2, lo at +8192
//   [262144, 278528)   WN: same layout, single 16KB image (k = 0..63)
__global__ __launch_bounds__(256) void presplit(const float *__restrict__ GW,
                                                const float *__restrict__ WN,
                                                char *__restrict__ ws) {
  const int b = blockIdx.x;
  const int tid = threadIdx.x;
  if (b < 64) {
    int idx = b * 256 + tid;  // f32x4 index into GW
    int e = idx >> 8;
    int c4 = idx & 255;
    f32x4 v = *reinterpret_cast<const f32x4 *>(GW + (size_t)idx * 4);
#pragma unroll
    for (int j = 0; j < 4; ++j) {
      int k = c4 * 4 + j;
      float vv = v[j];
      _Float16 hh = (_Float16)vv;
      _Float16 ll = (_Float16)((vv - (float)hh) * 4096.0f);
      int ck = k >> 6, kk = k & 63;
      int off = ck * 16384 + e * 128 + ((((kk >> 3) ^ (e & 7))) << 4) + ((kk & 7) << 1);
      *reinterpret_cast<_Float16 *>(ws + off) = hh;
      *reinterpret_cast<_Float16 *>(ws + off + 8192) = ll;
    }
  } else {
    int idx = (b - 64) * 256 + tid;  // f32x4 index into WN [k][e0..e0+3]
    int k = idx >> 4;
    int e0 = (idx & 15) << 2;
    f32x4 v = *reinterpret_cast<const f32x4 *>(WN + (size_t)k * 64 + e0);
#pragma unroll
    for (int j = 0; j < 4; ++j) {
      int e = e0 + j;
      float vv = v[j];
      _Float16 hh = (_Float16)vv;
      _Float16 ll = (_Float16)((vv - (float)hh) * 4096.0f);
      int off = 262144 + e * 128 + ((((k >> 3) ^ (e & 7))) << 4) + ((k & 7) << 1);
      *reinterpret_cast<_Float16 *>(ws + off) = hh;
      *reinterpret_cast<_Float16 *>(ws + off + 8192) = ll;
    }
  }
}

// BK=128 consolidation of R12: 8 steps of two 64-sub-chunks each.
// 128-row blocks (512 threads, 8 waves x 16 rows). B: 2 x 32KB LDS buffers,
// step n in buf[n%2] (sub-chunk s at s*16384, hi 8K + lo 8K). A: 2 step-banks
// (2 chunks each); every step issues the NEXT step's A-pair as 8 back-to-back
// dwordx4 = a CONTIGUOUS 512B window per X-row (R12's confirmed page lever),
// and the next step's B as 4 uniform DMA ops.
// vmcnt ledger (uniform fenced groups [B(n+1) 4, A(n+1) 8] per step):
//   CONV(n) implicitly drains A(n) (older than B(n+1): issued prev step).
//   end-of-step wait_vm<8> drains B(n+1)[4], keeps A(n+1)[8] across the
//   barrier. Prologue: [B0(4), A0(8)] -> wait_vm<8> drains B0 keeps A0.
//   Step 7 issues nothing; post-loop BAR precedes the epilogue aliasing.
// Barrier/wait events: 9 vs R12's 17 (same 512B bursts, same VGPR budget).
// Epilogue aliases: clean -> [0,32768) (wave w at w*4096); WN -> 32768.
__global__ __launch_bounds__(512, 4) void topk_gating(
    const float *__restrict__ X, const char *__restrict__ WS,
    const float *__restrict__ GB, const float *__restrict__ NZ,
    float *__restrict__ OUT) {
  __shared__ __align__(16) char lds[65536];
  const int tid = threadIdx.x;
  const int lane = tid & 63;
  const int wv = tid >> 6;  // 0..7
  const int q = lane >> 4;  // 0..3
  const int c = lane & 15;  // 0..15
  const int waveRow = blockIdx.x * 128 + wv * 16;

  f32x4 accH[4] = {};
  f32x4 accX[4] = {};
  f32x4 aA[2][4], aB[2][4];  // step-banks: A(n) in bank n%2 (static idx only)

  const float *xBase = X + (size_t)(waveRow + c) * 1024 + q * 8;
  const char *wsT = WS + tid * 16;  // B per-thread global src

#define LDA4(dst, p)                        \
  {                                         \
    dst[0] = *(const f32x4 *)((p) + 0);     \
    dst[1] = *(const f32x4 *)((p) + 4);     \
    dst[2] = *(const f32x4 *)((p) + 32);    \
    dst[3] = *(const f32x4 *)((p) + 36);    \
  }
// A-pair for step N: 8 dwordx4 back-to-back covering X cols [N*128, N*128+128)
// = contiguous 512B per row.
#define LDAP(BANK, N)                       \
  {                                         \
    const float *p_ = xBase + (N) * 128;    \
    LDA4(BANK[0], p_);                      \
    LDA4(BANK[1], p_ + 64);                 \
  }
// B for step N: 32KB image at WS + N*32768, 4 uniform ops (512thr x 16B = 8KB)
#define BDMA(N)                                                         \
  {                                                                     \
    char *bd_ = lds + ((N) % 2) * 32768;                                \
    _Pragma("unroll") for (int i_ = 0; i_ < 4; ++i_)                    \
        dma16(wsT + (N) * 32768 + i_ * 8192, bd_ + i_ * 8192 + tid * 16 \
              - lane * 16);                                             \
  }
#define CONV(A, ah, al)                                           \
  {                                                               \
    _Pragma("unroll") for (int ks_ = 0; ks_ < 2; ++ks_)           \
        _Pragma("unroll") for (int j_ = 0; j_ < 8; ++j_) {        \
      float xv_ = A[ks_ * 2 + (j_ >> 2)][j_ & 3];                 \
      _Float16 hh_ = (_Float16)xv_;                               \
      ah[ks_][j_] = hh_;                                          \
      al[ks_][j_] = (_Float16)((xv_ - (float)hh_) * 4096.0f);     \
    }                                                             \
  }
#define MFMAB(BUF, ah, al)                                                 \
  {                                                                        \
    _Pragma("unroll") for (int ks_ = 0; ks_ < 2; ++ks_)                    \
        _Pragma("unroll") for (int t_ = 0; t_ < 4; ++t_) {                 \
      int e_ = t_ * 16 + c;                                                \
      int off_ = (BUF) + e_ * 128 + ((((ks_ * 4 + q) ^ (e_ & 7))) << 4);   \
      half8v bh_ = *reinterpret_cast<half8v *>(lds + off_);                \
      half8v bl_ = *reinterpret_cast<half8v *>(lds + off_ + 8192);         \
      accH[t_] = mfma16(ah[ks_], bh_, accH[t_]);                           \
      accX[t_] = mfma16(ah[ks_], bl_, accX[t_]);                           \
      accX[t_] = mfma16(al[ks_], bh_, accX[t_]);                           \
    }                                                                      \
  }
// Compute step N on BANK (two sub-chunks, preserving chunk accumulation order)
#define STEPC2(N, BANK)                                   \
  {                                                       \
    half8v ah[2], al[2];                                  \
    CONV(BANK[0], ah, al);                                \
    MFMAB(((N) % 2) * 32768, ah, al);                     \
    CONV(BANK[1], ah, al);                                \
    MFMAB(((N) % 2) * 32768 + 16384, ah, al);             \
  }
#define STEP(N, CUR, NXT)                                 \
  {                                                       \
    if ((N) + 1 <= 7) {                                   \
      BDMA((N) + 1);                                      \
      FENCE();                                            \
      LDAP(NXT, (N) + 1);                                 \
      FENCE();                                            \
    }                                                     \
    STEPC2(N, CUR);                                       \
  }

  // prologue: [B0(4), A0(8)]; wait<8> drains B0, keeps A0 in flight.
  BDMA(0); FENCE();
  LDAP(aA, 0); FENCE();
  wait_vm<8>(); BAR();

  STEP(0, aA, aB) wait_vm<8>(); BAR();
  STEP(1, aB, aA) wait_vm<8>(); BAR();
  STEP(2, aA, aB) wait_vm<8>(); BAR();
  STEP(3, aB, aA) wait_vm<8>(); BAR();
  STEP(4, aA, aB) wait_vm<8>(); BAR();
  STEP(5, aB, aA) wait_vm<8>(); BAR();
  STEP(6, aA, aB) wait_vm<8>(); BAR();
  STEP(7, aB, aA)  // issues nothing; compute on buf1
  BAR();  // all waves done with both bufs before epilogue aliases LDS

  // ---- epilogue ----
  // issue order (pinned): GB(4), WN-DMA(2) | fence | NZ(16)
  float bs0 = GB[c], bs1 = GB[16 + c], bs2 = GB[32 + c], bs3 = GB[48 + c];
  // WN image (16KB) -> [32768, 49152): 2 uniform ops
  dma16(wsT + 262144, lds + 32768 + tid * 16 - lane * 16);
  dma16(wsT + 262144 + 8192, lds + 32768 + 8192 + tid * 16 - lane * 16);
  FENCE();
  float nz[4][4];
#pragma unroll
  for (int t = 0; t < 4; ++t)
#pragma unroll
    for (int r = 0; r < 4; ++r)
      nz[t][r] = NZ[(size_t)(waveRow + 4 * q + r) * 64 + t * 16 + c];

  float cl[4][4];  // [etile][reg]; element = (row 4q+r, expert 16t+c)
  const float bsv[4] = {bs0, bs1, bs2, bs3};
#pragma unroll
  for (int t = 0; t < 4; ++t)
#pragma unroll
    for (int r = 0; r < 4; ++r)
      cl[t][r] = accH[t][r] + accX[t][r] * INV4096 + bsv[t];

  // clean tile -> own-wave region of [0,32768) (buf0, dead), swizzled
  char *cb = lds + wv * 4096;
#pragma unroll
  for (int t = 0; t < 4; ++t)
#pragma unroll
    for (int r = 0; r < 4; ++r) {
      int row = 4 * q + r;
      int colf = t * 16 + c;
      int off = row * 256 + ((((colf >> 2) ^ row)) << 4) + ((colf & 3) << 2);
      *reinterpret_cast<float *>(cb + off) = cl[t][r];
    }
  wait_vm<16>();  // drains GB+WN; NZ(16) stays in flight
  BAR();

  // phase 2: raw = clean @ w_noise (split-fp16 MFMA, K=64); WN image at 32768
  f32x4 rH[4] = {};
  f32x4 rX[4] = {};
#pragma unroll
  for (int ks = 0; ks < 2; ++ks) {
    int slot0 = ks * 8 + q * 2;
    f32x4 va = *reinterpret_cast<f32x4 *>(cb + c * 256 + (((slot0 ^ c)) << 4));
    f32x4 vb = *reinterpret_cast<f32x4 *>(cb + c * 256 + ((((slot0 + 1) ^ c)) << 4));
    half8v ah, al;
#pragma unroll
    for (int j = 0; j < 4; ++j) {
      float v = va[j];
      _Float16 hh = (_Float16)v;
      ah[j] = hh;
      al[j] = (_Float16)((v - (float)hh) * 4096.0f);
      float v2 = vb[j];
      _Float16 h2 = (_Float16)v2;
      ah[4 + j] = h2;
      al[4 + j] = (_Float16)((v2 - (float)h2) * 4096.0f);
    }
#pragma unroll
    for (int t = 0; t < 4; ++t) {
      int e = t * 16 + c;
      int off = 32768 + e * 128 + ((((ks * 4 + q) ^ (e & 7))) << 4);
      half8v bh = *reinterpret_cast<half8v *>(lds + off);
      half8v bl = *reinterpret_cast<half8v *>(lds + off + 8192);
      rH[t] = mfma16(ah, bh, rH[t]);
      rX[t] = mfma16(ah, bl, rX[t]);
      rX[t] = mfma16(al, bh, rX[t]);
    }
  }

  float lg[4][4];  // [r][t]
#pragma unroll
  for (int t = 0; t < 4; ++t)
#pragma unroll
    for (int r = 0; r < 4; ++r) {
      float raw = rH[t][r] + rX[t][r] * INV4096;
      float sp = fmaxf(raw, 0.0f) + __logf(1.0f + __expf(-fabsf(raw)));
      lg[r][t] = cl[t][r] + nz[t][r] * (sp + 1e-5f);
    }

#pragma unroll
  for (int r = 0; r < 4; ++r) {
    float v0 = lg[r][0], v1 = lg[r][1], v2 = lg[r][2], v3 = lg[r][3];
    // top-2: in-lane over 4, then xor-shuffle over the 16-lane group
    float a = fmaxf(v0, v1), b_ = fminf(v0, v1);
    float d1 = fmaxf(v2, v3), d2 = fminf(v2, v3);
    float m1 = fmaxf(a, d1);
    float m2 = fmaxf(fminf(a, d1), fmaxf(b_, d2));
#pragma unroll
    for (int s = 1; s <= 8; s <<= 1) {
      float om1 = __shfl_xor(m1, s, 64);
      float om2 = __shfl_xor(m2, s, 64);
      float hi = fmaxf(m1, om1);
      float lo = fminf(m1, om1);
      float sec = (m1 >= om1) ? m2 : om2;
      m2 = fmaxf(lo, sec);
      m1 = hi;
    }
    // softmax(logits)
    float se[4], ssum = 0.f;
#pragma unroll
    for (int t = 0; t < 4; ++t) {
      se[t] = __expf(lg[r][t] - m1);
      ssum += se[t];
    }
#pragma unroll
    for (int s = 1; s <= 8; s <<= 1) ssum += __shfl_xor(ssum, s, 64);
    float inv = 1.0f / ssum;
    float ov[4];
#pragma unroll
    for (int t = 0; t < 4; ++t) {
      float sm = se[t] * inv;
      float vlog = ALPHA * __logf(1.0f + sm);
      float vexp = ALPHA * (__expf(sm) - 1.0f);
      ov[t] = (lg[r][t] < m2) ? vlog : vexp;
    }
    // gates = softmax(out)
    float g = fmaxf(fmaxf(ov[0], ov[1]), fmaxf(ov[2], ov[3]));
#pragma unroll
    for (int s = 1; s <= 8; s <<= 1) g = fmaxf(g, __shfl_xor(g, s, 64));
    float gsum = 0.f;
#pragma unroll
    for (int t = 0; t < 4; ++t) {
      ov[t] = __expf(ov[t] - g);
      gsum += ov[t];
    }
#pragma unroll
    for (int s = 1; s <= 8; s <<= 1) gsum += __shfl_xor(gsum, s, 64);
    float ginv = 1.0f / gsum;
    size_t rowOff = (size_t)(waveRow + 4 * q + r) * 64;
#pragma unroll
    for (int t = 0; t < 4; ++t)
      OUT[rowOff + t * 16 + c] = ov[t] * ginv;
  }
}

extern "C" void kernel_launch(void *const *d_in, const int *in_sizes, int n_in,
                              void *d_out, int out_size, void *d_ws,
                              size_t ws_size, hipStream_t stream) {
  const float *x = (const float *)d_in[0];
  const float *gw = (const float *)d_in[1];
  const float *gb = (const float *)d_in[2];
  const float *wn = (const float *)d_in[3];
  const float *nz = (const float *)d_in[4];
  float *out = (float *)d_out;
  char *ws = (char *)d_ws;
  const int N = in_sizes[0] / 1024;

  hipLaunchKernelGGL(presplit, dim3(68), dim3(256), 0, stream, gw, wn, ws);
  hipLaunchKernelGGL(topk_gating, dim3(N / 128), dim3(512), 0, stream, x, ws,
                     gb, nz, out);
}